// Round 4
// baseline (117.805 us; speedup 1.0000x reference)
//
#include <hip/hip_runtime.h>
#include <hip/hip_bf16.h>
#include <math.h>

// Conditional_Embedding_Contrastive_loss on MI355X (gfx950)
// N=4096, D=1024, C=1000. Output: scalar f32 loss.
//
// ws layout: [0,8MB) Xb bf16[N*D]; then nx[N], epos[N], sfull[N], smask[N] f32; lab[N] int.

#define NN   4096
#define DD   1024
#define NCLS 1000
#define EPSF 1e-8f

typedef short bf16x8 __attribute__((ext_vector_type(8)));
typedef float f32x4  __attribute__((ext_vector_type(4)));

// ---------- kernel 0: detect labels dtype (int32 vs int64) and compact ----------
__global__ void k_labels(const int* __restrict__ lraw, int* __restrict__ lab) {
  __shared__ int stride_s;
  if (threadIdx.x == 0) {
    int stride = 2;  // assume int64 (little-endian: value in even word, zero in odd)
    #pragma unroll
    for (int t = 0; t < 8; ++t) {
      int lo = lraw[2 * t], hi = lraw[2 * t + 1];
      if (hi != 0 || (unsigned)lo >= (unsigned)NCLS) { stride = 1; break; }
    }
    stride_s = stride;
  }
  __syncthreads();
  const int s = stride_s;
  for (int i = threadIdx.x; i < NN; i += blockDim.x) lab[i] = lraw[i * s];
}

// ---------- kernel 1: per-row norms, inst2embed_pos, f32->bf16 pack, zero-init ----------
__global__ __launch_bounds__(256) void k_rowstats(
    const float* __restrict__ X, const float* __restrict__ A,
    const float* __restrict__ Tp, ushort* __restrict__ Xb,
    float* __restrict__ nx, float* __restrict__ epos,
    float* __restrict__ sfull, float* __restrict__ smask,
    float* __restrict__ out) {
  const int i = blockIdx.x;
  const int t = threadIdx.x;
  const size_t base = (size_t)i * DD + t * 4;
  const float4 xv = *(const float4*)(X + base);
  const float4 av = *(const float4*)(A + base);
  float sxx = xv.x * xv.x + xv.y * xv.y + xv.z * xv.z + xv.w * xv.w;
  float saa = av.x * av.x + av.y * av.y + av.z * av.z + av.w * av.w;
  float sxa = xv.x * av.x + xv.y * av.y + xv.z * av.z + xv.w * av.w;

  // pack 4 bf16 (RNE) and store 8B
  ushort4 pk;
  { __hip_bfloat16 b;
    b = __float2bfloat16(xv.x); pk.x = *(const ushort*)&b;
    b = __float2bfloat16(xv.y); pk.y = *(const ushort*)&b;
    b = __float2bfloat16(xv.z); pk.z = *(const ushort*)&b;
    b = __float2bfloat16(xv.w); pk.w = *(const ushort*)&b; }
  *(ushort4*)(Xb + base) = pk;

  #pragma unroll
  for (int off = 32; off > 0; off >>= 1) {
    sxx += __shfl_down(sxx, off);
    saa += __shfl_down(saa, off);
    sxa += __shfl_down(sxa, off);
  }
  __shared__ float red[3][4];
  const int w = t >> 6;
  if ((t & 63) == 0) { red[0][w] = sxx; red[1][w] = saa; red[2][w] = sxa; }
  __syncthreads();
  if (t == 0) {
    const float a  = red[0][0] + red[0][1] + red[0][2] + red[0][3];
    const float bb = red[1][0] + red[1][1] + red[1][2] + red[1][3];
    const float c  = red[2][0] + red[2][1] + red[2][2] + red[2][3];
    const float nxi = sqrtf(a), nai = sqrtf(bb);
    nx[i] = nxi;
    epos[i] = expf((c / fmaxf(nxi * nai, EPSF)) / Tp[0]);
    sfull[i] = 0.f;
    smask[i] = 0.f;
    if (i == 0) out[0] = 0.f;
  }
}

// ---------- kernel 2: fused Gram (bf16 MFMA) + exp + masked/full row-sum accumulate ----------
#define BM 64
#define BN 64
#define BK 64
// LDS tile: row-major [64][64] bf16 = 128B/row = 8 x 16B slots/row.
// XOR swizzle: physical slot = logical slot ^ (row & 7). global_load_lds writes
// linearly (base + lane*16), so we pre-swizzle the GLOBAL source k-offset instead.

__global__ __launch_bounds__(256) void k_gram(
    const ushort* __restrict__ Xb, const float* __restrict__ nx,
    const int* __restrict__ lab, const int* __restrict__ cmask,
    const float* __restrict__ Tp,
    float* __restrict__ sfull, float* __restrict__ smask) {
  __shared__ __align__(16) char As[BM * BK * 2];
  __shared__ __align__(16) char Bs[BN * BK * 2];
  const int tid  = threadIdx.x;
  const int lane = tid & 63;
  const int w    = tid >> 6;       // wave 0..3
  const int wr   = w >> 1, wc = w & 1;
  const int i0   = blockIdx.y * BM;
  const int j0   = blockIdx.x * BN;

  // staging: wave w covers local rows [w*16, w*16+16); 2 ops of 8 rows (1KB each)
  const int srow   = (w << 4) + (lane >> 3);  // first-op local row
  const int schunk = lane & 7;                // physical 16B slot this lane fills
  const int sslot  = schunk ^ (srow & 7);     // logical k-slot to fetch ((srow+8)&7 == srow&7 so same xor for op 2)

  f32x4 acc[2][2];
  #pragma unroll
  for (int m = 0; m < 2; ++m)
    #pragma unroll
    for (int n = 0; n < 2; ++n)
      acc[m][n] = (f32x4){0.f, 0.f, 0.f, 0.f};

  char* lA1 = As + (w << 11);
  char* lA2 = As + (w << 11) + 1024;
  char* lB1 = Bs + (w << 11);
  char* lB2 = Bs + (w << 11) + 1024;

  for (int k0 = 0; k0 < DD; k0 += BK) {
    const char* gA1 = (const char*)(Xb + (size_t)(i0 + srow)     * DD + k0) + (sslot << 4);
    const char* gA2 = (const char*)(Xb + (size_t)(i0 + srow + 8) * DD + k0) + (sslot << 4);
    const char* gB1 = (const char*)(Xb + (size_t)(j0 + srow)     * DD + k0) + (sslot << 4);
    const char* gB2 = (const char*)(Xb + (size_t)(j0 + srow + 8) * DD + k0) + (sslot << 4);
    __builtin_amdgcn_global_load_lds((const __attribute__((address_space(1))) void*)gA1,
                                     (__attribute__((address_space(3))) void*)lA1, 16, 0, 0);
    __builtin_amdgcn_global_load_lds((const __attribute__((address_space(1))) void*)gA2,
                                     (__attribute__((address_space(3))) void*)lA2, 16, 0, 0);
    __builtin_amdgcn_global_load_lds((const __attribute__((address_space(1))) void*)gB1,
                                     (__attribute__((address_space(3))) void*)lB1, 16, 0, 0);
    __builtin_amdgcn_global_load_lds((const __attribute__((address_space(1))) void*)gB2,
                                     (__attribute__((address_space(3))) void*)lB2, 16, 0, 0);
    __syncthreads();  // compiler drains vmcnt before barrier

    #pragma unroll
    for (int ks = 0; ks < 2; ++ks) {
      bf16x8 af[2], bfr[2];
      #pragma unroll
      for (int m = 0; m < 2; ++m) {
        const int r    = (wr << 5) + (m << 4) + (lane & 15);
        const int slot = ((ks << 2) + (lane >> 4)) ^ (r & 7);
        af[m] = *(const bf16x8*)(As + r * 128 + (slot << 4));
      }
      #pragma unroll
      for (int n = 0; n < 2; ++n) {
        const int r    = (wc << 5) + (n << 4) + (lane & 15);
        const int slot = ((ks << 2) + (lane >> 4)) ^ (r & 7);
        bfr[n] = *(const bf16x8*)(Bs + r * 128 + (slot << 4));
      }
      #pragma unroll
      for (int m = 0; m < 2; ++m)
        #pragma unroll
        for (int n = 0; n < 2; ++n)
          acc[m][n] = __builtin_amdgcn_mfma_f32_16x16x32_bf16(af[m], bfr[n], acc[m][n], 0, 0, 0);
    }
    __syncthreads();
  }

  // epilogue: C/D mapping col=lane&15, row=(lane>>4)*4+reg (HW-verified)
  const float T = Tp[0];
  #pragma unroll
  for (int m = 0; m < 2; ++m) {
    #pragma unroll
    for (int r = 0; r < 4; ++r) {
      const int i = i0 + (wr << 5) + (m << 4) + ((lane >> 4) << 2) + r;
      const float nxi = nx[i];
      const int* mrow = cmask + (size_t)lab[i] * NN;
      float se = 0.f, sm = 0.f;
      #pragma unroll
      for (int n = 0; n < 2; ++n) {
        const int j = j0 + (wc << 5) + (n << 4) + (lane & 15);
        const float g = acc[m][n][r];
        float e = expf((g / fmaxf(nxi * nx[j], EPSF)) / T);
        if (i == j) e = 0.f;   // remove_diag
        se += e;
        sm += e * (float)mrow[j];
      }
      // reduce across the 16 lanes sharing this output row
      #pragma unroll
      for (int off = 1; off < 16; off <<= 1) {
        se += __shfl_xor(se, off);
        sm += __shfl_xor(sm, off);
      }
      if ((lane & 15) == 0) {
        atomicAdd(&sfull[i], se);
        atomicAdd(&smask[i], sm);
      }
    }
  }
}

// ---------- kernel 3: loss = mean(log(den) - log(num)) ----------
__global__ __launch_bounds__(256) void k_final(
    const float* __restrict__ sfull, const float* __restrict__ smask,
    const float* __restrict__ epos, float* __restrict__ out) {
  const int idx = blockIdx.x * 256 + threadIdx.x;
  const float ep  = epos[idx];
  const float num = smask[idx] + ep;
  const float den = ep + sfull[idx];
  float v = (logf(den) - logf(num)) * (1.0f / (float)NN);
  #pragma unroll
  for (int off = 32; off > 0; off >>= 1) v += __shfl_down(v, off);
  __shared__ float red[4];
  if ((threadIdx.x & 63) == 0) red[threadIdx.x >> 6] = v;
  __syncthreads();
  if (threadIdx.x == 0) atomicAdd(out, red[0] + red[1] + red[2] + red[3]);
}

extern "C" void kernel_launch(void* const* d_in, const int* in_sizes, int n_in,
                              void* d_out, int out_size, void* d_ws, size_t ws_size,
                              hipStream_t stream) {
  const float* X     = (const float*)d_in[0];
  const float* A     = (const float*)d_in[1];
  const int*   cmask = (const int*)d_in[2];
  const int*   lraw  = (const int*)d_in[3];
  const float* Tp    = (const float*)d_in[4];
  float* out = (float*)d_out;

  char* ws = (char*)d_ws;
  ushort* Xb   = (ushort*)ws;                         // 8 MB
  float* nx    = (float*)(ws + (size_t)NN * DD * 2);
  float* epos  = nx + NN;
  float* sfull = epos + NN;
  float* smask = sfull + NN;
  int*   lab   = (int*)(smask + NN);

  hipLaunchKernelGGL(k_labels,   dim3(1),            dim3(256), 0, stream, lraw, lab);
  hipLaunchKernelGGL(k_rowstats, dim3(NN),           dim3(256), 0, stream, X, A, Tp, Xb, nx, epos, sfull, smask, out);
  hipLaunchKernelGGL(k_gram,     dim3(NN/BN, NN/BM), dim3(256), 0, stream, Xb, nx, lab, cmask, Tp, sfull, smask);
  hipLaunchKernelGGL(k_final,    dim3(NN/256),       dim3(256), 0, stream, sfull, smask, epos, out);
}

// Round 5
// 81.043 us; speedup vs baseline: 1.4536x; 1.4536x over previous
//
#include <hip/hip_runtime.h>
#include <hip/hip_bf16.h>
#include <math.h>

// Conditional_Embedding_Contrastive_loss on MI355X (gfx950)
// N=4096, D=1024, C=1000. Output: scalar f32 loss.
// R4: 128x128 Gram tile (m97 structure), reciprocal-norm epilogue, __expf.

#define NN   4096
#define DD   1024
#define NCLS 1000
#define EPSF 1e-8f

typedef short bf16x8 __attribute__((ext_vector_type(8)));
typedef float f32x4  __attribute__((ext_vector_type(4)));

// ---------- kernel 0: detect labels dtype (int32 vs int64) and compact ----------
__global__ void k_labels(const int* __restrict__ lraw, int* __restrict__ lab) {
  __shared__ int stride_s;
  if (threadIdx.x == 0) {
    int stride = 2;  // assume int64 (little-endian: value in even word, zero in odd)
    #pragma unroll
    for (int t = 0; t < 8; ++t) {
      int lo = lraw[2 * t], hi = lraw[2 * t + 1];
      if (hi != 0 || (unsigned)lo >= (unsigned)NCLS) { stride = 1; break; }
    }
    stride_s = stride;
  }
  __syncthreads();
  const int s = stride_s;
  for (int i = threadIdx.x; i < NN; i += blockDim.x) lab[i] = lraw[i * s];
}

// ---------- kernel 1: per-row norms, inst2embed_pos, f32->bf16 pack, zero-init ----------
__global__ __launch_bounds__(256) void k_rowstats(
    const float* __restrict__ X, const float* __restrict__ A,
    const float* __restrict__ Tp, ushort* __restrict__ Xb,
    float* __restrict__ rnx, float* __restrict__ rnT,
    float* __restrict__ epos,
    float* __restrict__ sfull, float* __restrict__ smask,
    float* __restrict__ out) {
  const int i = blockIdx.x;
  const int t = threadIdx.x;
  const size_t base = (size_t)i * DD + t * 4;
  const float4 xv = *(const float4*)(X + base);
  const float4 av = *(const float4*)(A + base);
  float sxx = xv.x * xv.x + xv.y * xv.y + xv.z * xv.z + xv.w * xv.w;
  float saa = av.x * av.x + av.y * av.y + av.z * av.z + av.w * av.w;
  float sxa = xv.x * av.x + xv.y * av.y + xv.z * av.z + xv.w * av.w;

  // pack 4 bf16 (RNE) and store 8B
  ushort4 pk;
  { __hip_bfloat16 b;
    b = __float2bfloat16(xv.x); pk.x = *(const ushort*)&b;
    b = __float2bfloat16(xv.y); pk.y = *(const ushort*)&b;
    b = __float2bfloat16(xv.z); pk.z = *(const ushort*)&b;
    b = __float2bfloat16(xv.w); pk.w = *(const ushort*)&b; }
  *(ushort4*)(Xb + base) = pk;

  #pragma unroll
  for (int off = 32; off > 0; off >>= 1) {
    sxx += __shfl_down(sxx, off);
    saa += __shfl_down(saa, off);
    sxa += __shfl_down(sxa, off);
  }
  __shared__ float red[3][4];
  const int w = t >> 6;
  if ((t & 63) == 0) { red[0][w] = sxx; red[1][w] = saa; red[2][w] = sxa; }
  __syncthreads();
  if (t == 0) {
    const float a  = red[0][0] + red[0][1] + red[0][2] + red[0][3];
    const float bb = red[1][0] + red[1][1] + red[1][2] + red[1][3];
    const float c  = red[2][0] + red[2][1] + red[2][2] + red[2][3];
    const float nxi = sqrtf(a), nai = sqrtf(bb);
    const float rT  = 1.0f / Tp[0];
    const float r   = 1.0f / fmaxf(nxi, 1e-20f);
    rnx[i] = r;
    rnT[i] = r * rT;
    epos[i] = expf((c / fmaxf(nxi * nai, EPSF)) * rT);
    sfull[i] = 0.f;
    smask[i] = 0.f;
    if (i == 0) out[0] = 0.f;
  }
}

// ---------- kernel 2: fused Gram (bf16 MFMA, 128x128 tile) + exp + row-sum accumulate ----------
#define BM 128
#define BK 64
// LDS tile: row-major [128][64] bf16 = 128B/row = 8 x 16B slots/row.
// XOR swizzle: phys slot = logical ^ (row&7). global_load_lds writes linearly,
// so the GLOBAL source k-slot is pre-swizzled. Staging row ≡ lane>>3 (mod 8)
// so sslot = (lane&7) ^ (lane>>3), wave-independent.

__global__ __launch_bounds__(256) void k_gram(
    const ushort* __restrict__ Xb, const float* __restrict__ rnx,
    const float* __restrict__ rnT,
    const int* __restrict__ lab, const int* __restrict__ cmask,
    float* __restrict__ sfull, float* __restrict__ smask) {
  __shared__ __align__(16) char As[BM * BK * 2];   // 16 KB
  __shared__ __align__(16) char Bs[BM * BK * 2];   // 16 KB
  const int tid  = threadIdx.x;
  const int lane = tid & 63;
  const int w    = tid >> 6;       // wave 0..3
  const int wr   = w >> 1, wc = w & 1;
  const int i0   = blockIdx.y * BM;
  const int j0   = blockIdx.x * BM;

  const int sslot = (lane & 7) ^ (lane >> 3);  // pre-swizzled global k-slot

  f32x4 acc[4][4];
  #pragma unroll
  for (int m = 0; m < 4; ++m)
    #pragma unroll
    for (int n = 0; n < 4; ++n)
      acc[m][n] = (f32x4){0.f, 0.f, 0.f, 0.f};

  // hoisted per-chunk source pointers (chunk q: rows q*32 + w*8 + (lane>>3))
  const ushort* pA[4];
  const ushort* pB[4];
  #pragma unroll
  for (int q = 0; q < 4; ++q) {
    const int row = q * 32 + w * 8 + (lane >> 3);
    pA[q] = Xb + (size_t)(i0 + row) * DD + sslot * 8;
    pB[q] = Xb + (size_t)(j0 + row) * DD + sslot * 8;
  }

  for (int k0 = 0; k0 < DD; k0 += BK) {
    #pragma unroll
    for (int q = 0; q < 4; ++q) {
      __builtin_amdgcn_global_load_lds(
          (const __attribute__((address_space(1))) void*)(pA[q] + k0),
          (__attribute__((address_space(3))) void*)(As + (q * 4 + w) * 1024), 16, 0, 0);
      __builtin_amdgcn_global_load_lds(
          (const __attribute__((address_space(1))) void*)(pB[q] + k0),
          (__attribute__((address_space(3))) void*)(Bs + (q * 4 + w) * 1024), 16, 0, 0);
    }
    __syncthreads();  // compiler drains vmcnt before barrier

    #pragma unroll
    for (int ks = 0; ks < 2; ++ks) {
      const int slot = ((ks << 2) + (lane >> 4)) ^ (lane & 7);  // r&7 == lane&7
      bf16x8 af[4], bfr[4];
      #pragma unroll
      for (int m = 0; m < 4; ++m) {
        const int r = (wr << 6) + (m << 4) + (lane & 15);
        af[m] = *(const bf16x8*)(As + r * 128 + (slot << 4));
      }
      #pragma unroll
      for (int n = 0; n < 4; ++n) {
        const int r = (wc << 6) + (n << 4) + (lane & 15);
        bfr[n] = *(const bf16x8*)(Bs + r * 128 + (slot << 4));
      }
      #pragma unroll
      for (int m = 0; m < 4; ++m)
        #pragma unroll
        for (int n = 0; n < 4; ++n)
          acc[m][n] = __builtin_amdgcn_mfma_f32_16x16x32_bf16(af[m], bfr[n], acc[m][n], 0, 0, 0);
    }
    __syncthreads();
  }

  // epilogue: C/D mapping col=lane&15, row=(lane>>4)*4+reg (HW-verified)
  #pragma unroll
  for (int m = 0; m < 4; ++m) {
    #pragma unroll
    for (int r = 0; r < 4; ++r) {
      const int i = i0 + (wr << 6) + (m << 4) + ((lane >> 4) << 2) + r;
      const float rni = rnx[i];
      const int* mrow = cmask + (size_t)lab[i] * NN;
      float se = 0.f, sm = 0.f;
      #pragma unroll
      for (int n = 0; n < 4; ++n) {
        const int j = j0 + (wc << 6) + (n << 4) + (lane & 15);
        const float g = acc[m][n][r];
        float e = __expf(g * rni * rnT[j]);
        if (i == j) e = 0.f;   // remove_diag
        se += e;
        sm = fmaf(e, (float)mrow[j], sm);
      }
      // reduce across the 16 lanes sharing this output row
      #pragma unroll
      for (int off = 1; off < 16; off <<= 1) {
        se += __shfl_xor(se, off);
        sm += __shfl_xor(sm, off);
      }
      if ((lane & 15) == 0) {
        atomicAdd(&sfull[i], se);
        atomicAdd(&smask[i], sm);
      }
    }
  }
}

// ---------- kernel 3: loss = mean(log(den) - log(num)) ----------
__global__ __launch_bounds__(256) void k_final(
    const float* __restrict__ sfull, const float* __restrict__ smask,
    const float* __restrict__ epos, float* __restrict__ out) {
  const int idx = blockIdx.x * 256 + threadIdx.x;
  const float ep  = epos[idx];
  const float num = smask[idx] + ep;
  const float den = ep + sfull[idx];
  float v = (logf(den) - logf(num)) * (1.0f / (float)NN);
  #pragma unroll
  for (int off = 32; off > 0; off >>= 1) v += __shfl_down(v, off);
  __shared__ float red[4];
  if ((threadIdx.x & 63) == 0) red[threadIdx.x >> 6] = v;
  __syncthreads();
  if (threadIdx.x == 0) atomicAdd(out, red[0] + red[1] + red[2] + red[3]);
}

extern "C" void kernel_launch(void* const* d_in, const int* in_sizes, int n_in,
                              void* d_out, int out_size, void* d_ws, size_t ws_size,
                              hipStream_t stream) {
  const float* X     = (const float*)d_in[0];
  const float* A     = (const float*)d_in[1];
  const int*   cmask = (const int*)d_in[2];
  const int*   lraw  = (const int*)d_in[3];
  const float* Tp    = (const float*)d_in[4];
  float* out = (float*)d_out;

  char* ws = (char*)d_ws;
  ushort* Xb   = (ushort*)ws;                         // 8 MB
  float* rnx   = (float*)(ws + (size_t)NN * DD * 2);
  float* rnT   = rnx + NN;
  float* epos  = rnT + NN;
  float* sfull = epos + NN;
  float* smask = sfull + NN;
  int*   lab   = (int*)(smask + NN);

  hipLaunchKernelGGL(k_labels,   dim3(1),            dim3(256), 0, stream, lraw, lab);
  hipLaunchKernelGGL(k_rowstats, dim3(NN),           dim3(256), 0, stream, X, A, Tp, Xb, rnx, rnT, epos, sfull, smask, out);
  hipLaunchKernelGGL(k_gram,     dim3(NN/BM, NN/BM), dim3(256), 0, stream, Xb, rnx, rnT, lab, cmask, sfull, smask);
  hipLaunchKernelGGL(k_final,    dim3(NN/256),       dim3(256), 0, stream, sfull, smask, epos, out);
}